// Round 3
// baseline (712.529 us; speedup 1.0000x reference)
//
#include <hip/hip_runtime.h>

// p,q [64,64,25000] fp32. loss = sum_{rows} mask(row) * sum_v q*(log q - log p) / 4096
// mask(row) = 0 iff argmax_v p[row] == 0  <=>  p[row][0] >= max_v p[row] (first-occurrence rule).
//
// Memory-bound: 819.2 MB read once -> ~130 us floor at 6.3-6.5 TB/s
// (harness fills prove 6.5 TB/s sustainable). Bench total also contains ~510 us
// of harness re-poison fills (2 x ~255 us) that are not controllable from here.
//
// R2 -> R3: explicit 2-deep software pipeline. Named A/B register sets (static
// indexing, no runtime-indexed arrays), next iteration's 8 loads issued BEFORE
// computing the current set, P/Q pairwise-interleaved issue, remainder chunk
// prefetched in the prologue. Removes the per-iteration ~900-cycle HBM latency
// bubble that register reuse forced on the compiler.

#define VOCAB   25000
#define VOCAB4  6250            // 25000/4 exact; rows are 16B-aligned (100000 % 16 == 0)
#define BLOCK   256
#define BATCH   4
#define OFF     (BATCH * BLOCK) // 1024 chunks per iteration
#define FULL_ITERS 6            // 6144 chunks; remainder = 106
#define REM_BASE (FULL_ITERS * OFF)
#define REM_CNT  (VOCAB4 - REM_BASE)   // 106
#define LN2 0.69314718055994530942f

typedef float f4 __attribute__((ext_vector_type(4)));

#define NT(a) __builtin_nontemporal_load(a)

__global__ __launch_bounds__(BLOCK) void kl_row_kernel(
    const float* __restrict__ p, const float* __restrict__ q,
    float* __restrict__ partial)
{
    const int row = blockIdx.x;
    const size_t base = (size_t)row * VOCAB;
    const f4* __restrict__ p4 = reinterpret_cast<const f4*>(p + base);
    const f4* __restrict__ q4 = reinterpret_cast<const f4*>(q + base);
    const int tid = threadIdx.x;

    // p[row][0], needed for the mask (only lane 0's value is used)
    float p0 = (tid == 0) ? p[base] : 0.0f;

    float s[BATCH]  = {0.f, 0.f, 0.f, 0.f};
    float mx[BATCH] = {-1.f, -1.f, -1.f, -1.f};   // probabilities are positive

    f4 Pa[BATCH], Qa[BATCH], Pb[BATCH], Qb[BATCH];
    f4 Pr, Qr;
    const bool hasrem = tid < REM_CNT;

    // ---- prologue: iter 0 into set A; remainder chunk too (latency fully hidden)
    #pragma unroll
    for (int b = 0; b < BATCH; ++b) {
        Pa[b] = NT(&p4[tid + b * BLOCK]);
        Qa[b] = NT(&q4[tid + b * BLOCK]);
    }
    if (hasrem) {
        Pr = NT(&p4[REM_BASE + tid]);
        Qr = NT(&q4[REM_BASE + tid]);
    }

    // ---- main loop: 2 iterations per pass, prefetch-before-compute
    #pragma unroll
    for (int ii = 0; ii < FULL_ITERS / 2; ++ii) {
        // prefetch iter (2ii+1) into B before touching A's data
        const int vB = tid + (2 * ii + 1) * OFF;
        #pragma unroll
        for (int b = 0; b < BATCH; ++b) {
            Pb[b] = NT(&p4[vB + b * BLOCK]);
            Qb[b] = NT(&q4[vB + b * BLOCK]);
        }
        // compute set A (iter 2ii)
        #pragma unroll
        for (int b = 0; b < BATCH; ++b) {
            #pragma unroll
            for (int k = 0; k < 4; ++k)
                s[b] = fmaf(Qa[b][k], __log2f(Qa[b][k]) - __log2f(Pa[b][k]), s[b]);
            mx[b] = fmaxf(mx[b],
                     fmaxf(fmaxf(Pa[b][0], Pa[b][1]), fmaxf(Pa[b][2], Pa[b][3])));
        }
        // prefetch iter (2ii+2) into A (compile-time predicate; no OOB past row end)
        if (ii + 1 < FULL_ITERS / 2) {
            const int vA = tid + (2 * ii + 2) * OFF;
            #pragma unroll
            for (int b = 0; b < BATCH; ++b) {
                Pa[b] = NT(&p4[vA + b * BLOCK]);
                Qa[b] = NT(&q4[vA + b * BLOCK]);
            }
        }
        // compute set B (iter 2ii+1)
        #pragma unroll
        for (int b = 0; b < BATCH; ++b) {
            #pragma unroll
            for (int k = 0; k < 4; ++k)
                s[b] = fmaf(Qb[b][k], __log2f(Qb[b][k]) - __log2f(Pb[b][k]), s[b]);
            mx[b] = fmaxf(mx[b],
                     fmaxf(fmaxf(Pb[b][0], Pb[b][1]), fmaxf(Pb[b][2], Pb[b][3])));
        }
    }

    // ---- remainder: chunks 6144..6249 (loaded in prologue)
    if (hasrem) {
        #pragma unroll
        for (int k = 0; k < 4; ++k)
            s[0] = fmaf(Qr[k], __log2f(Qr[k]) - __log2f(Pr[k]), s[0]);
        mx[0] = fmaxf(mx[0], fmaxf(fmaxf(Pr[0], Pr[1]), fmaxf(Pr[2], Pr[3])));
    }

    float sum  = (s[0] + s[1]) + (s[2] + s[3]);
    float pmax = fmaxf(fmaxf(mx[0], mx[1]), fmaxf(mx[2], mx[3]));

    // wave(64) shuffle reduction
    #pragma unroll
    for (int off = 32; off > 0; off >>= 1) {
        sum  += __shfl_down(sum, off, 64);
        pmax  = fmaxf(pmax, __shfl_down(pmax, off, 64));
    }

    __shared__ float ssum[BLOCK / 64];
    __shared__ float smax[BLOCK / 64];
    const int wave = tid >> 6;
    const int lane = tid & 63;
    if (lane == 0) { ssum[wave] = sum; smax[wave] = pmax; }
    __syncthreads();

    if (tid == 0) {
        float stot = (ssum[0] + ssum[1]) + (ssum[2] + ssum[3]);
        float m = fmaxf(fmaxf(smax[0], smax[1]), fmaxf(smax[2], smax[3]));
        // mask = (argmax != 0); argmax==0 iff p0 == rowmax (first-occurrence rule)
        partial[row] = (p0 < m) ? stot * LN2 : 0.0f;
    }
}

__global__ __launch_bounds__(BLOCK) void kl_final_reduce(
    const float* __restrict__ partial, int rows, float* __restrict__ out)
{
    const int tid = threadIdx.x;
    float sum = 0.0f;
    for (int i = tid; i < rows; i += BLOCK) sum += partial[i];

    #pragma unroll
    for (int off = 32; off > 0; off >>= 1)
        sum += __shfl_down(sum, off, 64);

    __shared__ float ssum[BLOCK / 64];
    const int wave = tid >> 6;
    const int lane = tid & 63;
    if (lane == 0) ssum[wave] = sum;
    __syncthreads();

    if (tid == 0) {
        float s = (ssum[0] + ssum[1]) + (ssum[2] + ssum[3]);
        out[0] = s / (float)rows;
    }
}

extern "C" void kernel_launch(void* const* d_in, const int* in_sizes, int n_in,
                              void* d_out, int out_size, void* d_ws, size_t ws_size,
                              hipStream_t stream)
{
    const float* p = (const float*)d_in[0];
    const float* q = (const float*)d_in[1];
    float* out = (float*)d_out;
    float* partial = (float*)d_ws;          // rows * 4 B = 16 KB

    const int rows = in_sizes[0] / VOCAB;   // 64*64 = 4096

    kl_row_kernel<<<rows, BLOCK, 0, stream>>>(p, q, partial);
    kl_final_reduce<<<1, BLOCK, 0, stream>>>(partial, rows, out);
}